// Round 16
// baseline (129.730 us; speedup 1.0000x reference)
//
#include <hip/hip_runtime.h>

#define BB    32
#define CINc  64
#define HHc   32
#define WWc   32
#define COc   64
#define KSc   7
#define GGc   8
#define PADc  3
#define CPGc  8
#define NPIX  (HHc * WWc)      // 1024
#define HROWS 19               // staged rows per half-image block
#define NPOSP 640              // padded to 10 wave-tiles of 64

typedef _Float16 h8    __attribute__((ext_vector_type(8)));
typedef _Float16 h2    __attribute__((ext_vector_type(2)));
typedef float    f32x4 __attribute__((ext_vector_type(4)));

#if defined(__has_builtin)
#if __has_builtin(__builtin_amdgcn_fdot2)
#define HAVE_FDOT2 1
#endif
#endif

// Round 16: split-tap / 8-waves-per-SIMD. The work decomposition (1 thread per
// output pixel-group) pinned the machine at 262k threads = 4 waves/SIMD, and
// rounds 13-15 showed a flat latency-bound profile (all pipes <50%). This
// round doubles resident waves: block = 1024 thr = 512 px x 2 tap-halves
// (sub wave-uniform). sub0: ki 0..3, sub1: ki 4..6; partial (den, acc[8])
// combined through an LDS exchange + barrier; sub0 writes. Proj phase is the
// r15-verified MFMA slab (19 rows, 10 tiles over 16 waves). LDS 48 KB x 2
// blocks/CU = 96 KB; launch_bounds(1024,8) caps VGPR at 64.
__global__ __launch_bounds__(1024, 8) void fused_kernel(
    const float* __restrict__ x,      // [B][64][32][32]
    const float* __restrict__ wq,     // [64][64]
    const float* __restrict__ wk,
    const float* __restrict__ wv,
    const float* __restrict__ rel_h,  // [32][7]
    const float* __restrict__ rel_w,  // [32][7]
    const float* __restrict__ cv,     // [8]
    float* __restrict__ out)          // [B][64][32][32]
{
    __shared__ __attribute__((aligned(16))) f32x4 kplv[NPOSP];  // k[0:8] f16 10KB
    __shared__ __attribute__((aligned(16))) f32x4 vplv[NPOSP];  // v[0:8] f16 10KB
    __shared__ __attribute__((aligned(16))) f32x4 qplv[NPOSP];  // q[0:8] f16 10KB
    __shared__ __attribute__((aligned(16))) f32x4 exacc0[512];  // partial acc 16KB
    __shared__ __attribute__((aligned(16))) f32x4 exacc1[512];  //  (two halves)
    __shared__ float exden[512];                                // partial den 2KB

    const int bi   = blockIdx.x;
    const int xcd  = bi & 7;           // XCD swizzle: image's 16 blocks share L2
    const int t0   = bi >> 3;          // 0..63
    const int im   = t0 & 3;
    const int rest = t0 >> 2;          // 0..15
    const int g    = rest >> 1;
    const int hf   = rest & 1;
    const int b    = im * 8 + xcd;
    const int o0   = g * CPGc;
    const int tid  = threadIdx.x;      // 0..1023

    const int rowbase = hf ? (HHc - HROWS) : 0;   // 13 or 0
    const int pgbase  = rowbase * WWc;

    const int lane = tid & 63;
    const int wid  = tid >> 6;         // wave 0..15
    const int an   = lane & 15;        // A m-index / B,D n-index
    const int quad = lane >> 4;

    const float* xb = x + (size_t)b * CINc * NPIX;

    // ---------- B fragments (weights, f32 -> f16) ----------
    h8 bf[2][2];
    {
        const float* br0 = (an < 8) ? (wk + (o0 + an) * CINc)
                                    : (wv + (o0 + an - 8) * CINc);
        const float* br1 = wq + (o0 + ((an < 8) ? an : 0)) * CINc;
#pragma unroll
        for (int ks = 0; ks < 2; ++ks) {
            const int c0 = ks * 32 + quad * 8;
#pragma unroll
            for (int jj = 0; jj < 8; ++jj) {
                bf[0][ks][jj] = (_Float16)br0[c0 + jj];
                bf[1][ks][jj] = (_Float16)br1[c0 + jj];
            }
        }
    }

    // ---------- MFMA projection over the 19-row slab (10 tiles of 64 px) ----------
    {
        _Float16* kp16 = (_Float16*)kplv;
        _Float16* qp16 = (_Float16*)qplv;
        _Float16* vp16 = (_Float16*)vplv;

#pragma unroll 1
        for (int tt = wid; tt < 10; tt += 16) {   // waves 0..9 take one tile each
            const int pbase = pgbase + tt * 64;

            f32x4 acc0[4], acc1[4];
#pragma unroll
            for (int m = 0; m < 4; ++m) { acc0[m] = (f32x4)0.f; acc1[m] = (f32x4)0.f; }

#pragma unroll
            for (int m = 0; m < 4; ++m) {
                const int pg = min(pbase + m * 16 + an, NPIX - 1);  // clamp pad tile
                const float* xpx = xb + pg;
#pragma unroll
                for (int ks = 0; ks < 2; ++ks) {
                    const int c0 = ks * 32 + quad * 8;
                    h8 a;
#pragma unroll
                    for (int jj = 0; jj < 8; ++jj)
                        a[jj] = (_Float16)xpx[(c0 + jj) * NPIX];
                    acc0[m] = __builtin_amdgcn_mfma_f32_16x16x32_f16(a, bf[0][ks], acc0[m], 0, 0, 0);
                    acc1[m] = __builtin_amdgcn_mfma_f32_16x16x32_f16(a, bf[1][ks], acc1[m], 0, 0, 0);
                }
            }

#pragma unroll
            for (int m = 0; m < 4; ++m) {
#pragma unroll
                for (int r = 0; r < 4; ++r) {
                    const int lp = tt * 64 + m * 16 + quad * 4 + r;
                    const float d0 = acc0[m][r];
                    if (an < 8) {
                        kp16[lp * 8 + an] = (_Float16)d0;
                        qp16[lp * 8 + an] = (_Float16)acc1[m][r];
                    } else {
                        vp16[lp * 8 + (an - 8)] = (_Float16)d0;
                    }
                }
            }
        }
    }

    __syncthreads();

    // ---------- tap phase: 2 threads per pixel (sub = wave-uniform half) ----------
    const int sub = tid >> 9;          // 0: ki 0..3 + combine/write, 1: ki 4..6
    const int px  = tid & 511;
    const int w   = px & 31;
    const int lh  = px >> 5;           // 0..15
    const int h   = hf * 16 + lh;      // global row

    f32x4 qraw = qplv[(h - rowbase) * WWc + w];
    const h2* qh = (const h2*)&qraw;
    h2 q2[4] = {qh[0], qh[1], qh[2], qh[3]};
    float qf[CPGc];
#pragma unroll
    for (int jj = 0; jj < 4; ++jj) {
        qf[2 * jj]     = (float)q2[jj].x;
        qf[2 * jj + 1] = (float)q2[jj].y;
    }

    const bool use_h = (g < 4);
    const float* relp = use_h ? (rel_h + o0 * KSc) : (rel_w + (o0 - 32) * KSc);
    float qrel[KSc];
#pragma unroll
    for (int tt = 0; tt < KSc; ++tt) {
        float s = 0.f;
#pragma unroll
        for (int oi = 0; oi < CPGc; ++oi)
            s = fmaf(qf[oi], relp[oi * KSc + tt], s);
        qrel[tt] = s;
    }

    int  xcl[KSc];
    bool xin[KSc];
#pragma unroll
    for (int kj = 0; kj < KSc; ++kj) {
        const int xx = w + kj - PADc;
        xin[kj] = (xx >= 0) && (xx < WWc);
        xcl[kj] = min(max(xx, 0), WWc - 1);
    }

    float den = 0.f;
    float acc[CPGc];
#pragma unroll
    for (int oi = 0; oi < CPGc; ++oi) acc[oi] = 0.f;

    auto tap_row = [&](int ki) {
        const int y    = h + ki - PADc;
        const bool yin = (y >= 0) && (y < HHc);
        const int base = (min(max(y, 0), HHc - 1) - rowbase) * WWc;
#pragma unroll
        for (int kj = 0; kj < KSc; ++kj) {
            const int p = base + xcl[kj];
            const f32x4 kraw = kplv[p];
            const f32x4 vraw = vplv[p];
            const bool in = yin && xin[kj];

            float d = 0.f;
            const h2* kh = (const h2*)&kraw;
            const h2* vh = (const h2*)&vraw;
#if HAVE_FDOT2
            d = __builtin_amdgcn_fdot2(q2[0], kh[0], d, false);
            d = __builtin_amdgcn_fdot2(q2[1], kh[1], d, false);
            d = __builtin_amdgcn_fdot2(q2[2], kh[2], d, false);
            d = __builtin_amdgcn_fdot2(q2[3], kh[3], d, false);
#else
#pragma unroll
            for (int jj = 0; jj < 4; ++jj) {
                d = fmaf(qf[2 * jj],     (float)kh[jj].x, d);
                d = fmaf(qf[2 * jj + 1], (float)kh[jj].y, d);
            }
#endif
            const float s = (use_h ? qrel[ki] : qrel[kj]) + (in ? d : 0.f);
            const float e = __expf(s);
            den += e;
            const float ev = in ? e : 0.f;
            acc[0] = fmaf(ev, (float)vh[0].x, acc[0]);
            acc[1] = fmaf(ev, (float)vh[0].y, acc[1]);
            acc[2] = fmaf(ev, (float)vh[1].x, acc[2]);
            acc[3] = fmaf(ev, (float)vh[1].y, acc[3]);
            acc[4] = fmaf(ev, (float)vh[2].x, acc[4]);
            acc[5] = fmaf(ev, (float)vh[2].y, acc[5]);
            acc[6] = fmaf(ev, (float)vh[3].x, acc[6]);
            acc[7] = fmaf(ev, (float)vh[3].y, acc[7]);
        }
    };

    if (sub == 0) {
#pragma unroll
        for (int ki = 0; ki < 4; ++ki) tap_row(ki);
    } else {
#pragma unroll
        for (int ki = 4; ki < KSc; ++ki) tap_row(ki);
        exden[px]  = den;
        exacc0[px] = (f32x4){acc[0], acc[1], acc[2], acc[3]};
        exacc1[px] = (f32x4){acc[4], acc[5], acc[6], acc[7]};
    }

    __syncthreads();

    if (sub == 0) {
        den += exden[px];
        const f32x4 a0 = exacc0[px];
        const f32x4 a1 = exacc1[px];
        acc[0] += a0.x; acc[1] += a0.y; acc[2] += a0.z; acc[3] += a0.w;
        acc[4] += a1.x; acc[5] += a1.y; acc[6] += a1.z; acc[7] += a1.w;

        // ---------- adaptive mask + write ----------
        const int  r  = min(h, HHc - 1 - h);
        const int  lo = (h <= HHc - 1 - h) ? r : r + 1;
        const int  hi = HHc - 1 - r;
        const bool in_ring = (w >= lo) && (w <= hi);
        const float cvg = cv[g];
        float om = ((float)r - 15.0f + cvg * 16.0f) * (1.0f / 3.0f) + 1.0f;
        om = fminf(fmaxf(om, 0.0f), 1.0f);
        const float maskv = in_ring ? om : 1.0f;
        const float scale = maskv / den;

        float* ob = out + ((size_t)b * COc + o0) * NPIX + h * WWc + w;
#pragma unroll
        for (int oi = 0; oi < CPGc; ++oi)
            ob[(size_t)oi * NPIX] = acc[oi] * scale;
    }
}

extern "C" void kernel_launch(void* const* d_in, const int* in_sizes, int n_in,
                              void* d_out, int out_size, void* d_ws, size_t ws_size,
                              hipStream_t stream) {
    const float* x     = (const float*)d_in[0];
    const float* wq    = (const float*)d_in[1];
    const float* wk    = (const float*)d_in[2];
    const float* wv    = (const float*)d_in[3];
    const float* rel_h = (const float*)d_in[4];
    const float* rel_w = (const float*)d_in[5];
    const float* cv    = (const float*)d_in[6];
    float* out = (float*)d_out;

    fused_kernel<<<512, 1024, 0, stream>>>(x, wq, wk, wv, rel_h, rel_w, cv, out);
}

// Round 17
// 86.947 us; speedup vs baseline: 1.4921x; 1.4921x over previous
//
#include <hip/hip_runtime.h>

#define BB    32
#define CINc  64
#define HHc   32
#define WWc   32
#define COc   64
#define KSc   7
#define GGc   8
#define PADc  3
#define CPGc  8
#define NPIX  (HHc * WWc)      // 1024

typedef _Float16 h8    __attribute__((ext_vector_type(8)));
typedef _Float16 h2    __attribute__((ext_vector_type(2)));
typedef float    f32x4 __attribute__((ext_vector_type(4)));

#if defined(__has_builtin)
#if __has_builtin(__builtin_amdgcn_fdot2)
#define HAVE_FDOT2 1
#endif
#endif

// FINAL (= round 14, best verified: 87.39 us bench, absmax 0.039):
// MFMA projection: per block (image, group), X[1024x64].W[64x24] via
// v_mfma_f32_16x16x32_f16 (16 waves x 4 M-tiles x 2 N-tiles x 2 K-steps).
// All three LDS planes f16x8 = 16 B/position; taps read 2 x ds_read_b128
// (conflict-free), scores via fdot2, v accumulated with v_fma_mix_f32
// (f32 acc mandatory: e unnormalized, up to ~e^40). LDS 48 KB.
// Structural notes from the session:
//  - live set ~52 VGPR; any >=8 waves/SIMD scheme (<=64 VGPR cap) spills
//    catastrophically (r8/r11/r16: WRITE_SIZE 22-121 MB) -> 4 waves/SIMD max.
//  - at 4 waves/SIMD the kernel is a flat ~25 us latency-bound plateau
//    (r13-r15: tap-LDS cut, 2-blocks/CU, phase restructure all neutral).
//  - XCD swizzle (image's 8 group-blocks on one XCD) cut FETCH 25 -> 4.5 MB.
__global__ __launch_bounds__(1024, 4) void fused_kernel(
    const float* __restrict__ x,      // [B][64][32][32]
    const float* __restrict__ wq,     // [64][64]
    const float* __restrict__ wk,
    const float* __restrict__ wv,
    const float* __restrict__ rel_h,  // [32][7]
    const float* __restrict__ rel_w,  // [32][7]
    const float* __restrict__ cv,     // [8]
    float* __restrict__ out)          // [B][64][32][32]
{
    __shared__ __attribute__((aligned(16))) f32x4 kplv[NPIX];  // k[0:8] f16  16KB
    __shared__ __attribute__((aligned(16))) f32x4 vplv[NPIX];  // v[0:8] f16  16KB
    __shared__ __attribute__((aligned(16))) f32x4 qplv[NPIX];  // q[0:8] f16  16KB

    const int bi  = blockIdx.x;
    const int xcd = bi & 7;            // XCD swizzle (image's 8 groups share L2)
    const int t   = bi >> 3;
    const int im  = t & 3;
    const int g   = t >> 2;
    const int b   = im * 8 + xcd;
    const int o0  = g * CPGc;
    const int tid = threadIdx.x;       // = pixel index 0..1023
    const int w   = tid & 31;
    const int h   = tid >> 5;

    const int lane = tid & 63;
    const int wp   = (tid >> 6) << 6;  // wave's 64-pixel base
    const int an   = lane & 15;        // A m-index / B,D n-index
    const int quad = lane >> 4;

    const float* xb = x + (size_t)b * CINc * NPIX;

    // ---------- B fragments (weights, f32 -> f16) ----------
    // N-tile0: n<8 -> k channel n, n>=8 -> v channel n-8.  N-tile1: q (n>=8 pad).
    h8 bf[2][2];
    {
        const float* br0 = (an < 8) ? (wk + (o0 + an) * CINc)
                                    : (wv + (o0 + an - 8) * CINc);
        const float* br1 = wq + (o0 + ((an < 8) ? an : 0)) * CINc;
#pragma unroll
        for (int ks = 0; ks < 2; ++ks) {
            const int c0 = ks * 32 + quad * 8;
#pragma unroll
            for (int jj = 0; jj < 8; ++jj) {
                bf[0][ks][jj] = (_Float16)br0[c0 + jj];
                bf[1][ks][jj] = (_Float16)br1[c0 + jj];
            }
        }
    }

    // ---------- MFMA projection: 4 M-tiles x 2 N-tiles, K=64 in 2 steps ----------
    f32x4 acc0[4], acc1[4];
#pragma unroll
    for (int m = 0; m < 4; ++m) { acc0[m] = (f32x4)0.f; acc1[m] = (f32x4)0.f; }

#pragma unroll
    for (int m = 0; m < 4; ++m) {
        const float* xpx = xb + wp + m * 16 + an;   // this lane's pixel column
#pragma unroll
        for (int ks = 0; ks < 2; ++ks) {
            const int c0 = ks * 32 + quad * 8;
            h8 a;
#pragma unroll
            for (int jj = 0; jj < 8; ++jj)
                a[jj] = (_Float16)xpx[(c0 + jj) * NPIX];
            acc0[m] = __builtin_amdgcn_mfma_f32_16x16x32_f16(a, bf[0][ks], acc0[m], 0, 0, 0);
            acc1[m] = __builtin_amdgcn_mfma_f32_16x16x32_f16(a, bf[1][ks], acc1[m], 0, 0, 0);
        }
    }

    // ---------- scatter D -> LDS planes (C-layout: pix = quad*4+reg) ----------
    {
        _Float16* kp16 = (_Float16*)kplv;
        _Float16* qp16 = (_Float16*)qplv;
        _Float16* vp16 = (_Float16*)vplv;
#pragma unroll
        for (int m = 0; m < 4; ++m) {
#pragma unroll
            for (int r = 0; r < 4; ++r) {
                const int pix = wp + m * 16 + quad * 4 + r;
                const float d0 = acc0[m][r];
                if (an < 8) {
                    kp16[pix * 8 + an] = (_Float16)d0;
                    qp16[pix * 8 + an] = (_Float16)acc1[m][r];
                } else {
                    vp16[pix * 8 + (an - 8)] = (_Float16)d0;
                }
            }
        }
    }

    __syncthreads();

    // ---------- own-pixel q ----------
    f32x4 qraw = qplv[tid];
    const h2* qh = (const h2*)&qraw;
    h2 q2[4] = {qh[0], qh[1], qh[2], qh[3]};
    float qf[CPGc];
#pragma unroll
    for (int jj = 0; jj < 4; ++jj) {
        qf[2 * jj]     = (float)q2[jj].x;
        qf[2 * jj + 1] = (float)q2[jj].y;
    }

    // qrel[t] = sum_oi q[oi] * rel[oi][t]
    const bool use_h = (g < 4);
    const float* relp = use_h ? (rel_h + o0 * KSc) : (rel_w + (o0 - 32) * KSc);
    float qrel[KSc];
#pragma unroll
    for (int tt = 0; tt < KSc; ++tt) {
        float s = 0.f;
#pragma unroll
        for (int oi = 0; oi < CPGc; ++oi)
            s = fmaf(qf[oi], relp[oi * KSc + tt], s);
        qrel[tt] = s;
    }

    // per-kj clamped col + in-bounds mask
    int  xcl[KSc];
    bool xin[KSc];
#pragma unroll
    for (int kj = 0; kj < KSc; ++kj) {
        const int xx = w + kj - PADc;
        xin[kj] = (xx >= 0) && (xx < WWc);
        xcl[kj] = min(max(xx, 0), WWc - 1);
    }

    // ---------- taps: clamped reads + predication ----------
    float den = 0.f;
    float acc[CPGc];
#pragma unroll
    for (int oi = 0; oi < CPGc; ++oi) acc[oi] = 0.f;

#pragma unroll
    for (int ki = 0; ki < KSc; ++ki) {
        const int y    = h + ki - PADc;
        const bool yin = (y >= 0) && (y < HHc);
        const int base = min(max(y, 0), HHc - 1) * WWc;
#pragma unroll
        for (int kj = 0; kj < KSc; ++kj) {
            const int p = base + xcl[kj];
            const f32x4 kraw = kplv[p];
            const f32x4 vraw = vplv[p];
            const bool in = yin && xin[kj];

            float d = 0.f;
            const h2* kh = (const h2*)&kraw;
            const h2* vh = (const h2*)&vraw;
#if HAVE_FDOT2
            d = __builtin_amdgcn_fdot2(q2[0], kh[0], d, false);
            d = __builtin_amdgcn_fdot2(q2[1], kh[1], d, false);
            d = __builtin_amdgcn_fdot2(q2[2], kh[2], d, false);
            d = __builtin_amdgcn_fdot2(q2[3], kh[3], d, false);
#else
#pragma unroll
            for (int jj = 0; jj < 4; ++jj) {
                d = fmaf(qf[2 * jj],     (float)kh[jj].x, d);
                d = fmaf(qf[2 * jj + 1], (float)kh[jj].y, d);
            }
#endif
            const float s = (use_h ? qrel[ki] : qrel[kj]) + (in ? d : 0.f);
            const float e = __expf(s);      // OOB: e = exp(qrel) (ref zero-pad)
            den += e;
            const float ev = in ? e : 0.f;  // OOB taps contribute no v
            // v_fma_mix_f32: f16 v operand fused into f32 FMA (no cvt insts)
            acc[0] = fmaf(ev, (float)vh[0].x, acc[0]);
            acc[1] = fmaf(ev, (float)vh[0].y, acc[1]);
            acc[2] = fmaf(ev, (float)vh[1].x, acc[2]);
            acc[3] = fmaf(ev, (float)vh[1].y, acc[3]);
            acc[4] = fmaf(ev, (float)vh[2].x, acc[4]);
            acc[5] = fmaf(ev, (float)vh[2].y, acc[5]);
            acc[6] = fmaf(ev, (float)vh[3].x, acc[6]);
            acc[7] = fmaf(ev, (float)vh[3].y, acc[7]);
        }
    }

    // ---------- adaptive mask + write ----------
    const int  r  = min(h, HHc - 1 - h);
    const int  lo = (h <= HHc - 1 - h) ? r : r + 1;
    const int  hi = HHc - 1 - r;
    const bool in_ring = (w >= lo) && (w <= hi);
    const float cvg = cv[g];
    float om = ((float)r - 15.0f + cvg * 16.0f) * (1.0f / 3.0f) + 1.0f;
    om = fminf(fmaxf(om, 0.0f), 1.0f);
    const float maskv = in_ring ? om : 1.0f;
    const float scale = maskv / den;

    float* ob = out + ((size_t)b * COc + o0) * NPIX + tid;
#pragma unroll
    for (int oi = 0; oi < CPGc; ++oi)
        ob[(size_t)oi * NPIX] = acc[oi] * scale;
}

extern "C" void kernel_launch(void* const* d_in, const int* in_sizes, int n_in,
                              void* d_out, int out_size, void* d_ws, size_t ws_size,
                              hipStream_t stream) {
    const float* x     = (const float*)d_in[0];
    const float* wq    = (const float*)d_in[1];
    const float* wk    = (const float*)d_in[2];
    const float* wv    = (const float*)d_in[3];
    const float* rel_h = (const float*)d_in[4];
    const float* rel_w = (const float*)d_in[5];
    const float* cv    = (const float*)d_in[6];
    float* out = (float*)d_out;

    fused_kernel<<<256, 1024, 0, stream>>>(x, wq, wk, wv, rel_h, rel_w, cv, out);
}